// Round 3
// baseline (1983.532 us; speedup 1.0000x reference)
//
#include <hip/hip_runtime.h>

// GRU recurrence, fused persistent kernel (round 3).
// DTYPE: all device buffers are FLOAT32 (reference declares jnp.float32; round-0
// zero-output error == max|ref| under f32 read; f32-as-bf16 misread explains the
// NaNs of rounds 1-2). MFMA path: weights pre-converted f32->bf16 into d_ws once
// per launch; x converted inline; carry h kept f32 in LDS (bf16 shadow for MFMA
// operands only); f32 accumulate; f32 outputs.

typedef __attribute__((ext_vector_type(8))) short short8;   // 8 x bf16 MFMA frag
typedef __attribute__((ext_vector_type(4))) float f32x4;

constexpr int B_ = 1024, T_ = 128, I_ = 128, H_ = 256, OUT_ = 64;
constexpr int ROWS = 16;        // batch rows per block
constexpr int NBLK = B_ / ROWS; // 64 blocks
constexpr int HPH = 264;        // bf16 LDS row stride (shorts; 16B-aligned rows)
constexpr int HPF = 260;        // f32  LDS row stride (floats; 16B-aligned rows)

#define DEVI __device__ __forceinline__

DEVI unsigned short f2b(float f) {  // RNE float->bf16 (finite values only here)
    unsigned u = __builtin_bit_cast(unsigned, f);
    u += 0x7fffu + ((u >> 16) & 1u);
    return (unsigned short)(u >> 16);
}
DEVI float sigmoidf_(float x) { return 1.f / (1.f + __expf(-x)); }
DEVI float tanhf_(float x) { float e = __expf(2.f * x); return (e - 1.f) / (e + 1.f); }

DEVI short8 ldg8(const unsigned short* p) {   // 8 bf16 = one 16B load
    return __builtin_bit_cast(short8, *reinterpret_cast<const uint4*>(p));
}
DEVI short8 cvt8(const float* p) {            // 8 f32 -> bf16 fragment
    f32x4 lo = *reinterpret_cast<const f32x4*>(p);
    f32x4 hi = *reinterpret_cast<const f32x4*>(p + 4);
    union { unsigned short s[8]; short8 v; } r;
#pragma unroll
    for (int e = 0; e < 4; ++e) { r.s[e] = f2b(lo[e]); r.s[4 + e] = f2b(hi[e]); }
    return r.v;
}
DEVI f32x4 mfma(short8 a, short8 b, f32x4 c) {
    return __builtin_amdgcn_mfma_f32_16x16x32_bf16(a, b, c, 0, 0, 0);
}

// ---- weight pre-conversion: f32 -> bf16 into d_ws (n % 8 == 0) ----
__global__ void cvt_w(const float* __restrict__ src, unsigned short* __restrict__ dst, int n) {
    int i = (blockIdx.x * blockDim.x + threadIdx.x) * 8;
    if (i >= n) return;
    f32x4 lo = *reinterpret_cast<const f32x4*>(src + i);
    f32x4 hi = *reinterpret_cast<const f32x4*>(src + i + 4);
    union { unsigned short s[8]; uint4 v; } r;
#pragma unroll
    for (int e = 0; e < 4; ++e) { r.s[e] = f2b(lo[e]); r.s[4 + e] = f2b(hi[e]); }
    *reinterpret_cast<uint4*>(dst + i) = r.v;
}

__global__ __launch_bounds__(512, 2) void gru_fused(
    const float* __restrict__ s0,             // [B][H] f32
    const float* __restrict__ a,              // [B][T][I] f32
    const unsigned short* __restrict__ w_ih,  // [3H][I] bf16 (ws)  rows: r,z,n
    const unsigned short* __restrict__ w_hh,  // [3H][H] bf16 (ws)
    const unsigned short* __restrict__ w_rw,  // [OUT][H] bf16 (ws)
    const unsigned short* __restrict__ w_st,  // [H][H] bf16 (ws)
    float* __restrict__ out_r,                // [T][OUT] f32
    float* __restrict__ out_s)                // [B][T][H] f32
{
    __shared__ float          h32[ROWS][HPF];   // carry h, f32 (exact)
    __shared__ unsigned short h16[ROWS][HPH];   // carry h, bf16 shadow (MFMA operand)
    __shared__ unsigned short hn16[ROWS][HPH];  // h_new, bf16 (MFMA operand)

    const int tid = threadIdx.x;
    const int w = tid >> 6;     // wave 0..7
    const int l = tid & 63;
    const int m = l & 15;       // MFMA A row / B col within tile
    const int kg = l >> 4;      // k-group 0..3 (8 contiguous k each)
    const int R0 = blockIdx.x * ROWS;

    const int pr = tid >> 5;          // io phase: row 0..15
    const int pc = (tid & 31) * 8;    // io phase: col 0..248 step 8

    // init h = s  (f32 + bf16 shadow)
    {
        f32x4 lo = *reinterpret_cast<const f32x4*>(&s0[(size_t)(R0 + pr) * H_ + pc]);
        f32x4 hi = *reinterpret_cast<const f32x4*>(&s0[(size_t)(R0 + pr) * H_ + pc + 4]);
        *reinterpret_cast<f32x4*>(&h32[pr][pc]) = lo;
        *reinterpret_cast<f32x4*>(&h32[pr][pc + 4]) = hi;
#pragma unroll
        for (int e = 0; e < 4; ++e) {
            h16[pr][pc + e] = f2b(lo[e]);
            h16[pr][pc + 4 + e] = f2b(hi[e]);
        }
    }
    __syncthreads();

    for (int t = 0; t < T_; ++t) {
        // ---- phase 1: gate GEMMs + in-register GRU elementwise -> hn16 ----
        short8 xa[4], ha[8];
        {
            const float* xb = a + (size_t)(R0 + m) * T_ * I_ + (size_t)t * I_ + kg * 8;
#pragma unroll
            for (int kt = 0; kt < 4; ++kt) xa[kt] = cvt8(xb + kt * 32);
#pragma unroll
            for (int kt = 0; kt < 8; ++kt)
                ha[kt] = ldg8(&h16[m][kt * 32 + kg * 8]);
        }
#pragma unroll
        for (int u = 0; u < 2; ++u) {
            const int gcol = (2 * w + u) * 16 + m;   // gate index 0..255
            f32x4 ar  = {0.f, 0.f, 0.f, 0.f};
            f32x4 az  = {0.f, 0.f, 0.f, 0.f};
            f32x4 ani = {0.f, 0.f, 0.f, 0.f};
            f32x4 anh = {0.f, 0.f, 0.f, 0.f};
#pragma unroll
            for (int kt = 0; kt < 4; ++kt) {   // x part, K=128
                const unsigned short* wp = w_ih + (size_t)gcol * I_ + kt * 32 + kg * 8;
                ar  = mfma(xa[kt], ldg8(wp),            ar);
                az  = mfma(xa[kt], ldg8(wp + 256 * I_), az);
                ani = mfma(xa[kt], ldg8(wp + 512 * I_), ani);
            }
#pragma unroll
            for (int kt = 0; kt < 8; ++kt) {   // h part, K=256
                const unsigned short* wp = w_hh + (size_t)gcol * H_ + kt * 32 + kg * 8;
                ar  = mfma(ha[kt], ldg8(wp),            ar);
                az  = mfma(ha[kt], ldg8(wp + 256 * H_), az);
                anh = mfma(ha[kt], ldg8(wp + 512 * H_), anh);
            }
            // D mapping: row = kg*4+v (batch), col = m -> gate gcol
#pragma unroll
            for (int v = 0; v < 4; ++v) {
                const int rr = kg * 4 + v;
                const float hold = h32[rr][gcol];
                const float rg = sigmoidf_(ar[v]);
                const float zg = sigmoidf_(az[v]);
                const float ng = tanhf_(ani[v] + rg * anh[v]);
                hn16[rr][gcol] = f2b((1.f - zg) * ng + zg * hold);
            }
        }
        __syncthreads();

        // ---- phase 2: s_next = sig(h_new @ w_state^T); block0: r_t ----
        {
            short8 na[8];
#pragma unroll
            for (int kt = 0; kt < 8; ++kt)
                na[kt] = ldg8(&hn16[m][kt * 32 + kg * 8]);
#pragma unroll
            for (int u = 0; u < 2; ++u) {
                const int j = (2 * w + u) * 16 + m;  // state col 0..255
                f32x4 acc = {0.f, 0.f, 0.f, 0.f};
#pragma unroll
                for (int kt = 0; kt < 8; ++kt)
                    acc = mfma(na[kt], ldg8(w_st + (size_t)j * H_ + kt * 32 + kg * 8), acc);
#pragma unroll
                for (int v = 0; v < 4; ++v) {
                    const float s = sigmoidf_(acc[v]);
                    h32[kg * 4 + v][j] = s;            // new carry (f32)
                    h16[kg * 4 + v][j] = f2b(s);       // bf16 shadow
                }
            }
            if (blockIdx.x == 0 && w < 4) {  // r_t = sig(h_new[0] @ w_reward^T)
                const int o = w * 16 + m;    // 0..63
                f32x4 acc = {0.f, 0.f, 0.f, 0.f};
#pragma unroll
                for (int kt = 0; kt < 8; ++kt)
                    acc = mfma(na[kt], ldg8(w_rw + (size_t)o * H_ + kt * 32 + kg * 8), acc);
                if (kg == 0)  // batch row 0 = D row 0 = lanes 0..15, reg 0
                    out_r[t * OUT_ + o] = sigmoidf_(acc[0]);
            }
        }
        __syncthreads();

        // ---- phase 3: stream s_next (f32) to s_list[b][t][:] (coalesced) ----
        {
            float* dst = &out_s[((size_t)(R0 + pr) * T_ + t) * H_ + pc];
            *reinterpret_cast<f32x4*>(dst) = *reinterpret_cast<const f32x4*>(&h32[pr][pc]);
            *reinterpret_cast<f32x4*>(dst + 4) = *reinterpret_cast<const f32x4*>(&h32[pr][pc + 4]);
        }
    }
}

extern "C" void kernel_launch(void* const* d_in, const int* in_sizes, int n_in,
                              void* d_out, int out_size, void* d_ws, size_t ws_size,
                              hipStream_t stream) {
    const float* s0  = (const float*)d_in[0];
    const float* a   = (const float*)d_in[1];
    const float* wih = (const float*)d_in[2];
    const float* whh = (const float*)d_in[3];
    const float* wrw = (const float*)d_in[4];
    const float* wst = (const float*)d_in[5];

    // bf16 weight copies in workspace
    unsigned short* ws16 = (unsigned short*)d_ws;
    unsigned short* wih16 = ws16;                 // 768*128  = 98304
    unsigned short* whh16 = wih16 + 98304;        // 768*256  = 196608
    unsigned short* wrw16 = whh16 + 196608;       // 64*256   = 16384
    unsigned short* wst16 = wrw16 + 16384;        // 256*256  = 65536

    cvt_w<<<98304  / (256 * 8), 256, 0, stream>>>(wih, wih16, 98304);
    cvt_w<<<196608 / (256 * 8), 256, 0, stream>>>(whh, whh16, 196608);
    cvt_w<<<16384  / (256 * 8), 256, 0, stream>>>(wrw, wrw16, 16384);
    cvt_w<<<65536  / (256 * 8), 256, 0, stream>>>(wst, wst16, 65536);

    float* out = (float*)d_out;
    gru_fused<<<NBLK, 512, 0, stream>>>(s0, a, wih16, whh16, wrw16, wst16,
                                        out, out + (size_t)T_ * OUT_);
}